// Round 15
// baseline (719.607 us; speedup 1.0000x reference)
//
#include <hip/hip_runtime.h>
#include <math.h>

#define NN 50000
#define NE 300000
#define DIN 768
#define DHID 256
#define DOUT 128
#define H0 8
#define D0 32
#define OFFST (NN + 4)

typedef __attribute__((ext_vector_type(8))) short bf16x8;
typedef __attribute__((ext_vector_type(8))) unsigned short u16x8;
typedef __attribute__((ext_vector_type(4))) float f32x4;

__device__ __forceinline__ unsigned short f2bf(float f) {
    unsigned u = __float_as_uint(f);
    unsigned r = (u + 0x7fffu + ((u >> 16) & 1u)) >> 16;
    return (unsigned short)r;
}
__device__ __forceinline__ float bf2f(unsigned short u) {
    return __uint_as_float(((unsigned)u) << 16);
}

__device__ __forceinline__ void gload16(const void* g, void* l) {
    __builtin_amdgcn_global_load_lds(
        (const __attribute__((address_space(1))) unsigned int*)g,
        (__attribute__((address_space(3))) unsigned int*)l, 16, 0, 0);
}

__device__ __forceinline__ void store_bf8(unsigned short* dst, float4 lo, float4 hi) {
    u16x8 o;
    o[0] = f2bf(lo.x); o[1] = f2bf(lo.y); o[2] = f2bf(lo.z); o[3] = f2bf(lo.w);
    o[4] = f2bf(hi.x); o[5] = f2bf(hi.y); o[6] = f2bf(hi.z); o[7] = f2bf(hi.w);
    *(u16x8*)dst = o;
}

// three transposed-converts in one dispatch (y=0,1: Kab x Nab; y=2: Kc x Ncc)
__global__ void transconv3_kernel(const float* __restrict__ Wa, const float* __restrict__ Wb,
                                  const float* __restrict__ Wc,
                                  unsigned short* __restrict__ Ta, unsigned short* __restrict__ Tb,
                                  unsigned short* __restrict__ Tc,
                                  int Kab, int Nab, int Kc, int Ncc)
{
    int y = blockIdx.y;
    const float* W = (y == 0) ? Wa : ((y == 1) ? Wb : Wc);
    unsigned short* T = (y == 0) ? Ta : ((y == 1) ? Tb : Tc);
    int K = (y == 2) ? Kc : Kab;
    int Nc = (y == 2) ? Ncc : Nab;
    int gid = blockIdx.x * 256 + threadIdx.x;
    if (gid >= K * Nc) return;
    int k = gid / Nc, n = gid - k * Nc;
    T[(size_t)n * K + k] = f2bf(W[gid]);
}

// ---------------- L0 GEMM: 128x128 tile, 512 threads / 8 waves (64x32 per wave) ----------------
// Same memory structure as the 158us variant (A reg-staged dist-2 + bf16 ds_write; B 3-deep
// gload_lds; chunk-XOR LDS; counted vmcnt(3) raw barriers) but 2x the waves per block for
// latency hiding. LDS 40KB. K=768 fully unrolled.
__global__ __launch_bounds__(512) void gemm_l0_kernel(
    const float* __restrict__ A0, const float* __restrict__ A1,
    const unsigned short* __restrict__ Bt0, const unsigned short* __restrict__ Bt1,
    const float* __restrict__ bias0, const float* __restrict__ bias1,
    unsigned short* __restrict__ C0, unsigned short* __restrict__ C1)
{
    constexpr int K  = DIN;     // 768
    constexpr int Nc = DHID;    // 256
    constexpr int NT = K / 32;  // 24
    __shared__ __align__(16) unsigned short As[2][128 * 32];
    __shared__ __align__(16) unsigned short Bs[3][128 * 32];
    const int z = blockIdx.z;
    const float* A = z ? A1 : A0;
    const unsigned short* Bt = z ? Bt1 : Bt0;
    const float* bias = z ? bias1 : bias0;
    unsigned short* C = z ? C1 : C0;
    const int t = threadIdx.x;               // 0..511
    const int lane = t & 63, w = t >> 6;     // 8 waves
    const int wr = w >> 2, wc = w & 3;       // 2 x 4 -> wave tile 64x32
    const int bm = blockIdx.y * 128, bn = blockIdx.x * 128;

    f32x4 acc[4][2];
    #pragma unroll
    for (int m = 0; m < 4; ++m)
        #pragma unroll
        for (int n = 0; n < 2; ++n)
            acc[m][n] = (f32x4){0.f, 0.f, 0.f, 0.f};

    // A: 512 chunks (128 rows x 4 chunks of 8 f32); thread owns chunk t.
    // LDS chunk (row, slot) holds global chunk slot^((row>>1)&3).
    const int arow = t >> 2;
    const int ags = (t & 3) ^ ((arow >> 1) & 3);
    int ar = bm + arow; if (ar >= NN) ar = NN - 1;
    const float* pA = A + (size_t)ar * K + ags * 8;
    // B: 512 chunks (128 rows x 4 chunks of 8 bf16); thread owns chunk t.
    const int brow = t >> 2;
    const int bgs = (t & 3) ^ ((brow >> 1) & 3);
    const unsigned short* pB = Bt + (size_t)(bn + brow) * K + bgs * 8;

    const int rA = wr * 64 + (lane & 15);
    const int rB = wc * 32 + (lane & 15);
    const int gw = lane >> 4;

    float4 ra[2][2];
    // prologue: A(0) temps + store; B(0),B(1) gloads; A(1)->ra[1]
    {
        float4 t0 = *(const float4*)(pA);
        float4 t1 = *(const float4*)(pA + 4);
        gload16(pB, &Bs[0][(size_t)t * 8]);
        ra[1][0] = *(const float4*)(pA + 32);
        ra[1][1] = *(const float4*)(pA + 36);
        gload16(pB + 32, &Bs[1][(size_t)t * 8]);
        store_bf8(&As[0][(size_t)t * 8], t0, t1);
    }
    asm volatile("s_waitcnt vmcnt(3) lgkmcnt(0)\n\ts_barrier" ::: "memory");

    #pragma unroll
    for (int ti = 0; ti < NT; ++ti) {
        const int rcv = ti & 1;        // LDS A buffer read this step; reg set receiving A(ti+2)
        const int con = rcv ^ 1;       // reg set holding A(ti+1), LDS A buffer written this step
        if (ti + 2 < NT) {
            const int nk = (ti + 2) * 32;
            ra[rcv][0] = *(const float4*)(pA + nk);
            ra[rcv][1] = *(const float4*)(pA + nk + 4);
            gload16(pB + nk, &Bs[(ti + 2) % 3][(size_t)t * 8]);
        }
        bf16x8 afr[4], bfr[2];
        #pragma unroll
        for (int m = 0; m < 4; ++m) {
            int r = rA + m * 16;
            afr[m] = *(const bf16x8*)&As[rcv][r * 32 + ((gw ^ ((r >> 1) & 3)) * 8)];
        }
        #pragma unroll
        for (int n = 0; n < 2; ++n) {
            int r = rB + n * 16;
            bfr[n] = *(const bf16x8*)&Bs[ti % 3][r * 32 + ((gw ^ ((r >> 1) & 3)) * 8)];
        }
        #pragma unroll
        for (int m = 0; m < 4; ++m)
            #pragma unroll
            for (int n = 0; n < 2; ++n)
                acc[m][n] = __builtin_amdgcn_mfma_f32_16x16x32_bf16(afr[m], bfr[n], acc[m][n], 0, 0, 0);
        if (ti + 1 < NT) {
            store_bf8(&As[con][(size_t)t * 8], ra[con][0], ra[con][1]);
            if (ti + 2 < NT) asm volatile("s_waitcnt vmcnt(3) lgkmcnt(0)\n\ts_barrier" ::: "memory");
            else             asm volatile("s_waitcnt vmcnt(0) lgkmcnt(0)\n\ts_barrier" ::: "memory");
        }
    }

    #pragma unroll
    for (int m = 0; m < 4; ++m) {
        #pragma unroll
        for (int j = 0; j < 4; ++j) {
            int row = bm + wr * 64 + m * 16 + (lane >> 4) * 4 + j;
            if (row >= NN) continue;
            #pragma unroll
            for (int n = 0; n < 2; ++n) {
                int col = bn + wc * 32 + n * 16 + (lane & 15);
                C[(size_t)row * Nc + col] = f2bf(acc[m][n][j] + bias[col]);
            }
        }
    }
}

// ---------------- MFMA GEMM (bf16 A), double-buffered gload_lds ----------------
__global__ __launch_bounds__(256) void gemm_bf16_kernel(
    const unsigned short* __restrict__ A0, const unsigned short* __restrict__ A1,
    const unsigned short* __restrict__ Bt0, const unsigned short* __restrict__ Bt1,
    const float* __restrict__ bias0, const float* __restrict__ bias1,
    unsigned short* __restrict__ C0, unsigned short* __restrict__ C1,
    int M, int K, int Nc)
{
    __shared__ __align__(16) unsigned short As[2][128 * 32];
    __shared__ __align__(16) unsigned short Bs[2][128 * 32];
    const int z = blockIdx.z;
    const unsigned short* A  = z ? A1  : A0;
    const unsigned short* Bt = z ? Bt1 : Bt0;
    const float* bias = z ? bias1 : bias0;
    unsigned short* C = z ? C1 : C0;
    const int t = threadIdx.x;
    const int lane = t & 63, w = t >> 6;
    const int wr = w >> 1, wc = w & 1;
    const int bm = blockIdx.y * 128, bn = blockIdx.x * 128;

    f32x4 acc[4][4];
    #pragma unroll
    for (int m = 0; m < 4; ++m)
        #pragma unroll
        for (int n = 0; n < 4; ++n)
            acc[m][n] = (f32x4){0.f, 0.f, 0.f, 0.f};

    const int c0 = w * 64 + lane, c1 = c0 + 256;
    const int row0 = c0 >> 2, row1 = c1 >> 2;
    const int g0 = (c0 & 3) ^ ((row0 >> 1) & 3);
    const int g1 = (c1 & 3) ^ ((row1 >> 1) & 3);
    const int ar0 = (bm + row0 < M) ? (bm + row0) : (M - 1);
    const int ar1 = (bm + row1 < M) ? (bm + row1) : (M - 1);
    const unsigned short* pA0 = A + (size_t)ar0 * K + g0 * 8;
    const unsigned short* pA1 = A + (size_t)ar1 * K + g1 * 8;
    const unsigned short* pB0 = Bt + (size_t)(bn + row0) * K + g0 * 8;
    const unsigned short* pB1 = Bt + (size_t)(bn + row1) * K + g1 * 8;

    const int rA = wr * 64 + (lane & 15);
    const int rB = wc * 64 + (lane & 15);
    const int gw = lane >> 4;
    const int nt = K >> 5;

    gload16(pA0, &As[0][c0 * 8]);
    gload16(pA1, &As[0][c1 * 8]);
    gload16(pB0, &Bs[0][c0 * 8]);
    gload16(pB1, &Bs[0][c1 * 8]);
    __syncthreads();
    for (int ti = 0; ti < nt; ++ti) {
        const int cur = ti & 1;
        if (ti + 1 < nt) {
            const int nk = (ti + 1) << 5;
            const int nb = cur ^ 1;
            gload16(pA0 + nk, &As[nb][c0 * 8]);
            gload16(pA1 + nk, &As[nb][c1 * 8]);
            gload16(pB0 + nk, &Bs[nb][c0 * 8]);
            gload16(pB1 + nk, &Bs[nb][c1 * 8]);
        }
        bf16x8 afr[4], bfr[4];
        #pragma unroll
        for (int m = 0; m < 4; ++m) {
            int r = rA + m * 16;
            afr[m] = *(const bf16x8*)&As[cur][r * 32 + ((gw ^ ((r >> 1) & 3)) * 8)];
        }
        #pragma unroll
        for (int n = 0; n < 4; ++n) {
            int r = rB + n * 16;
            bfr[n] = *(const bf16x8*)&Bs[cur][r * 32 + ((gw ^ ((r >> 1) & 3)) * 8)];
        }
        #pragma unroll
        for (int m = 0; m < 4; ++m)
            #pragma unroll
            for (int n = 0; n < 4; ++n)
                acc[m][n] = __builtin_amdgcn_mfma_f32_16x16x32_bf16(afr[m], bfr[n], acc[m][n], 0, 0, 0);
        __syncthreads();
    }
    #pragma unroll
    for (int m = 0; m < 4; ++m) {
        #pragma unroll
        for (int j = 0; j < 4; ++j) {
            int row = bm + wr * 64 + m * 16 + (lane >> 4) * 4 + j;
            if (row >= M) continue;
            #pragma unroll
            for (int n = 0; n < 4; ++n) {
                int col = bn + wc * 64 + n * 16 + (lane & 15);
                C[(size_t)row * Nc + col] = f2bf(acc[m][n][j] + bias[col]);
            }
        }
    }
}

// ---------------- sem GEMM (batched pair via blockIdx.z) ----------------
__global__ __launch_bounds__(256) void sem2_bf16_kernel(
    const unsigned short* __restrict__ Aa, const unsigned short* __restrict__ Ab,
    const unsigned short* __restrict__ Bt,
    const float* __restrict__ bk, float* __restrict__ partial0,
    int M, int K, int Nc)
{
    __shared__ __align__(16) unsigned short As[2][128 * 32];
    __shared__ __align__(16) unsigned short Bs[2][128 * 32];
    __shared__ float red[128];
    const int z = blockIdx.z;
    const unsigned short* A = z ? Ab : Aa;
    float* partial = partial0 + z * Nc;
    const int t = threadIdx.x;
    const int lane = t & 63, w = t >> 6;
    const int wr = w >> 1, wc = w & 1;
    const int bm = blockIdx.y * 128, bn = blockIdx.x * 128;

    f32x4 acc[4][4];
    #pragma unroll
    for (int m = 0; m < 4; ++m)
        #pragma unroll
        for (int n = 0; n < 4; ++n)
            acc[m][n] = (f32x4){0.f, 0.f, 0.f, 0.f};

    const int c0 = w * 64 + lane, c1 = c0 + 256;
    const int row0 = c0 >> 2, row1 = c1 >> 2;
    const int g0 = (c0 & 3) ^ ((row0 >> 1) & 3);
    const int g1 = (c1 & 3) ^ ((row1 >> 1) & 3);
    const int ar0 = (bm + row0 < M) ? (bm + row0) : (M - 1);
    const int ar1 = (bm + row1 < M) ? (bm + row1) : (M - 1);
    const unsigned short* pA0 = A + (size_t)ar0 * K + g0 * 8;
    const unsigned short* pA1 = A + (size_t)ar1 * K + g1 * 8;
    const unsigned short* pB0 = Bt + (size_t)(bn + row0) * K + g0 * 8;
    const unsigned short* pB1 = Bt + (size_t)(bn + row1) * K + g1 * 8;

    const int rA = wr * 64 + (lane & 15);
    const int rB = wc * 64 + (lane & 15);
    const int gw = lane >> 4;
    const int nt = K >> 5;

    gload16(pA0, &As[0][c0 * 8]);
    gload16(pA1, &As[0][c1 * 8]);
    gload16(pB0, &Bs[0][c0 * 8]);
    gload16(pB1, &Bs[0][c1 * 8]);
    __syncthreads();
    for (int ti = 0; ti < nt; ++ti) {
        const int cur = ti & 1;
        if (ti + 1 < nt) {
            const int nk = (ti + 1) << 5;
            const int nb = cur ^ 1;
            gload16(pA0 + nk, &As[nb][c0 * 8]);
            gload16(pA1 + nk, &As[nb][c1 * 8]);
            gload16(pB0 + nk, &Bs[nb][c0 * 8]);
            gload16(pB1 + nk, &Bs[nb][c1 * 8]);
        }
        bf16x8 afr[4], bfr[4];
        #pragma unroll
        for (int m = 0; m < 4; ++m) {
            int r = rA + m * 16;
            afr[m] = *(const bf16x8*)&As[cur][r * 32 + ((gw ^ ((r >> 1) & 3)) * 8)];
        }
        #pragma unroll
        for (int n = 0; n < 4; ++n) {
            int r = rB + n * 16;
            bfr[n] = *(const bf16x8*)&Bs[cur][r * 32 + ((gw ^ ((r >> 1) & 3)) * 8)];
        }
        #pragma unroll
        for (int m = 0; m < 4; ++m)
            #pragma unroll
            for (int n = 0; n < 4; ++n)
                acc[m][n] = __builtin_amdgcn_mfma_f32_16x16x32_bf16(afr[m], bfr[n], acc[m][n], 0, 0, 0);
        __syncthreads();
    }
    if (t < 128) red[t] = 0.f;
    __syncthreads();
    #pragma unroll
    for (int n = 0; n < 4; ++n) {
        int lcol = wc * 64 + n * 16 + (lane & 15);
        float b = bk[bn + lcol];
        float s = 0.f;
        #pragma unroll
        for (int m = 0; m < 4; ++m) {
            #pragma unroll
            for (int j = 0; j < 4; ++j) {
                int row = bm + wr * 64 + m * 16 + (lane >> 4) * 4 + j;
                if (row < M) s += tanhf(acc[m][n][j] + b);
            }
        }
        atomicAdd(&red[lcol], s);
    }
    __syncthreads();
    if (t < 128) atomicAdd(&partial[bn + t], red[t]);
}

// ---------------- batched CSR build ----------------
__global__ void hist3_kernel(const int* __restrict__ d0, const int* __restrict__ d1,
                             const int* __restrict__ d2, int* __restrict__ deg3)
{
    int gid = blockIdx.x * 256 + threadIdx.x;
    if (gid >= 3 * NE) return;
    int rel = gid / NE, e = gid - rel * NE;
    const int* dst = (rel == 0) ? d0 : ((rel == 1) ? d1 : d2);
    atomicAdd(&deg3[rel * NN + dst[e]], 1);
}

__global__ void block_sum3_kernel(const int* __restrict__ deg3, int* __restrict__ bsum3)
{
    __shared__ int buf[256];
    int rel = blockIdx.y;
    int i = blockIdx.x * 256 + threadIdx.x;
    buf[threadIdx.x] = (i < NN) ? deg3[rel * NN + i] : 0;
    __syncthreads();
    for (int s = 128; s > 0; s >>= 1) {
        if (threadIdx.x < s) buf[threadIdx.x] += buf[threadIdx.x + s];
        __syncthreads();
    }
    if (threadIdx.x == 0) bsum3[rel * 256 + blockIdx.x] = buf[0];
}

__global__ void scan_bsum3_kernel(const int* __restrict__ bsum3, int* __restrict__ boff3, int nb)
{
    __shared__ int buf[256];
    int rel = blockIdx.y;
    int tid = threadIdx.x;
    int v = (tid < nb) ? bsum3[rel * 256 + tid] : 0;
    buf[tid] = v;
    __syncthreads();
    for (int off = 1; off < 256; off <<= 1) {
        int t = (tid >= off) ? buf[tid - off] : 0;
        __syncthreads();
        buf[tid] += t;
        __syncthreads();
    }
    if (tid < nb) boff3[rel * 256 + tid] = buf[tid] - v;
}

__global__ void scan_final3_kernel(const int* __restrict__ deg3, const int* __restrict__ boff3,
                                   int* __restrict__ offs3)
{
    __shared__ int buf[256];
    int rel = blockIdx.y;
    int tid = threadIdx.x, b = blockIdx.x;
    int i = b * 256 + tid;
    int v = (i < NN) ? deg3[rel * NN + i] : 0;
    buf[tid] = v;
    __syncthreads();
    for (int off = 1; off < 256; off <<= 1) {
        int t = (tid >= off) ? buf[tid - off] : 0;
        __syncthreads();
        buf[tid] += t;
        __syncthreads();
    }
    int* offs = offs3 + rel * OFFST;
    if (i < NN) offs[i] = boff3[rel * 256 + b] + buf[tid] - v;
    if (i == NN - 1) offs[NN] = boff3[rel * 256 + b] + buf[tid];
}

__global__ void place3_kernel(const int* __restrict__ s0, const int* __restrict__ s1,
                              const int* __restrict__ s2,
                              const int* __restrict__ offs3, int* __restrict__ cnt3,
                              int* __restrict__ esrc3)
{
    int rel = blockIdx.y;
    int e = blockIdx.x * 256 + threadIdx.x;
    if (e >= NE) return;
    const int* srcdst = (rel == 0) ? s0 : ((rel == 1) ? s1 : s2);
    int src = srcdst[e];
    int d = srcdst[NE + e];
    int p = offs3[rel * OFFST + d] + atomicAdd(&cnt3[rel * NN + d], 1);
    esrc3[rel * NE + p] = src;
}

// ---------------- fused per-layer node scores ----------------
__global__ void scores_L0_kernel(
    const unsigned short* __restrict__ xp, const unsigned short* __restrict__ xa,
    const float* __restrict__ a_dw, const float* __restrict__ a_swb,
    const float* __restrict__ a_sc, const float* __restrict__ a_dc,
    const float* __restrict__ a_sw, const float* __restrict__ a_dwb,
    float* __restrict__ sW_dst, float* __restrict__ sWB_src,
    float* __restrict__ sC_src, float* __restrict__ sC_dst,
    float* __restrict__ sW_src, float* __restrict__ sWB_dst)
{
    int gid = blockIdx.x * 256 + threadIdx.x;
    int half = NN * H0;
    if (gid >= 2 * half) return;
    if (gid < half) {
        int node = gid >> 3, h = gid & 7;
        const unsigned short* xr = xp + (size_t)node * DHID + h * D0;
        float xv[D0];
        #pragma unroll
        for (int j = 0; j < 4; ++j) {
            u16x8 v = ((const u16x8*)xr)[j];
            #pragma unroll
            for (int k = 0; k < 8; ++k) xv[j * 8 + k] = bf2f(v[k]);
        }
        const float* p0 = a_dw  + h * D0;
        const float* p1 = a_swb + h * D0;
        const float* p2 = a_sc  + h * D0;
        const float* p3 = a_dc  + h * D0;
        float d0 = 0.f, d1 = 0.f, d2 = 0.f, d3 = 0.f;
        #pragma unroll
        for (int k = 0; k < D0; ++k) {
            float x = xv[k];
            d0 += x * p0[k]; d1 += x * p1[k]; d2 += x * p2[k]; d3 += x * p3[k];
        }
        sW_dst[gid] = d0; sWB_src[gid] = d1; sC_src[gid] = d2; sC_dst[gid] = d3;
    } else {
        int g = gid - half;
        int node = g >> 3, h = g & 7;
        const unsigned short* xr = xa + (size_t)node * DHID + h * D0;
        float xv[D0];
        #pragma unroll
        for (int j = 0; j < 4; ++j) {
            u16x8 v = ((const u16x8*)xr)[j];
            #pragma unroll
            for (int k = 0; k < 8; ++k) xv[j * 8 + k] = bf2f(v[k]);
        }
        const float* p0 = a_sw  + h * D0;
        const float* p1 = a_dwb + h * D0;
        float d0 = 0.f, d1 = 0.f;
        #pragma unroll
        for (int k = 0; k < D0; ++k) {
            float x = xv[k];
            d0 += x * p0[k]; d1 += x * p1[k];
        }
        sW_src[g] = d0; sWB_dst[g] = d1;
    }
}

__global__ void scores_L1_kernel(
    const unsigned short* __restrict__ xp, const unsigned short* __restrict__ xa,
    const float* __restrict__ a_dw, const float* __restrict__ a_swb,
    const float* __restrict__ a_sc, const float* __restrict__ a_dc,
    const float* __restrict__ a_sw, const float* __restrict__ a_dwb,
    float* __restrict__ sW_dst, float* __restrict__ sWB_src,
    float* __restrict__ sC_src, float* __restrict__ sC_dst,
    float* __restrict__ sW_src, float* __restrict__ sWB_dst)
{
    int gid = blockIdx.x * 256 + threadIdx.x;
    if (gid >= 2 * NN) return;
    if (gid < NN) {
        const unsigned short* xr = xp + (size_t)gid * DOUT;
        float d0 = 0.f, d1 = 0.f, d2 = 0.f, d3 = 0.f;
        for (int j = 0; j < DOUT / 8; ++j) {
            u16x8 v = ((const u16x8*)xr)[j];
            #pragma unroll
            for (int k = 0; k < 8; ++k) {
                float x = bf2f(v[k]);
                int c = j * 8 + k;
                d0 += x * a_dw[c]; d1 += x * a_swb[c]; d2 += x * a_sc[c]; d3 += x * a_dc[c];
            }
        }
        sW_dst[gid] = d0; sWB_src[gid] = d1; sC_src[gid] = d2; sC_dst[gid] = d3;
    } else {
        int g = gid - NN;
        const unsigned short* xr = xa + (size_t)g * DOUT;
        float d0 = 0.f, d1 = 0.f;
        for (int j = 0; j < DOUT / 8; ++j) {
            u16x8 v = ((const u16x8*)xr)[j];
            #pragma unroll
            for (int k = 0; k < 8; ++k) {
                float x = bf2f(v[k]);
                int c = j * 8 + k;
                d0 += x * a_sw[c]; d1 += x * a_dwb[c];
            }
        }
        sW_src[g] = d0; sWB_dst[g] = d1;
    }
}

// ---------------- batched per-(dst,head) segment softmax -> alpha ----------------
__global__ void seg_alpha3_kernel(
    const int* __restrict__ offs3, const int* __restrict__ esrc3,
    const float* __restrict__ ss0, const float* __restrict__ ss1, const float* __restrict__ ss2,
    const float* __restrict__ sd0, const float* __restrict__ sd1, const float* __restrict__ sd2,
    float* __restrict__ alpha3, int H)
{
    int rel = blockIdx.y;
    const int* offs = offs3 + rel * OFFST;
    const int* esrc = esrc3 + rel * NE;
    const float* ssrc = (rel == 0) ? ss0 : ((rel == 1) ? ss1 : ss2);
    const float* sdst = (rel == 0) ? sd0 : ((rel == 1) ? sd1 : sd2);
    float* alpha = alpha3 + (size_t)rel * NE * H0;
    int gid = blockIdx.x * 256 + threadIdx.x;
    if (gid >= NN * H) return;
    int d = gid / H, h = gid - d * H;
    int beg = offs[d], end = offs[d + 1];
    float sd = sdst[gid];
    float m = -INFINITY, den = 0.f;
    for (int i = beg; i < end; ++i) {
        int s = esrc[i];
        float v = ssrc[s * H + h] + sd;
        v = (v >= 0.f) ? v : 0.2f * v;
        if (v > m) { den = den * expf(m - v) + 1.f; m = v; }
        else       den += expf(v - m);
    }
    float inv = 1.f / (den + 1e-16f);
    for (int i = beg; i < end; ++i) {
        int s = esrc[i];
        float v = ssrc[s * H + h] + sd;
        v = (v >= 0.f) ? v : 0.2f * v;
        alpha[(size_t)i * H + h] = expf(v - m) * inv;
    }
}

// ---------------- batched weighted gather, 2-deep software pipeline ----------------
template<int CPL, int HH, int DSH>
__global__ __launch_bounds__(256) void gather3_kernel(
    const int* __restrict__ offs3, const int* __restrict__ esrc3,
    const float* __restrict__ alpha3,
    const unsigned short* __restrict__ x0, const unsigned short* __restrict__ x1,
    const unsigned short* __restrict__ x2,
    unsigned short* __restrict__ o0, unsigned short* __restrict__ o1,
    unsigned short* __restrict__ o2, int C)
{
    int rel = blockIdx.y;
    const int* offs = offs3 + rel * OFFST;
    const int* esrc = esrc3 + rel * NE;
    const float* alpha = alpha3 + (size_t)rel * NE * H0;
    const unsigned short* x = (rel == 0) ? x0 : ((rel == 1) ? x1 : x2);
    unsigned short* outp = (rel == 0) ? o0 : ((rel == 1) ? o1 : o2);

    int wid = threadIdx.x >> 6, lane = threadIdx.x & 63;
    int d = blockIdx.x * 4 + wid;
    int c0 = lane * CPL;
    int h = c0 >> DSH;
    int beg = offs[d], end = offs[d + 1];
    float acc0 = 0.f, acc1 = 0.f, acc2 = 0.f, acc3 = 0.f;
    int n = end - beg;
    if (n > 0) {
        int sA = esrc[beg];
        float aA = alpha[(size_t)beg * HH + h];
        int sB = sA; float aB = 0.f;
        if (n > 1) { sB = esrc[beg + 1]; aB = alpha[(size_t)(beg + 1) * HH + h]; }
        if (CPL == 4) {
            ushort4 xc = *(const ushort4*)(x + (size_t)sA * C + c0);
            for (int i = beg; i < end; ++i) {
                ushort4 xn = xc;
                if (i + 1 < end) xn = *(const ushort4*)(x + (size_t)sB * C + c0);
                int sN = sB; float aN = 0.f;
                if (i + 2 < end) { sN = esrc[i + 2]; aN = alpha[(size_t)(i + 2) * HH + h]; }
                acc0 += aA * bf2f(xc.x); acc1 += aA * bf2f(xc.y);
                acc2 += aA * bf2f(xc.z); acc3 += aA * bf2f(xc.w);
                xc = xn; aA = aB; sB = sN; aB = aN;
            }
        } else {
            ushort2 xc = *(const ushort2*)(x + (size_t)sA * C + c0);
            for (int i = beg; i < end; ++i) {
                ushort2 xn = xc;
                if (i + 1 < end) xn = *(const ushort2*)(x + (size_t)sB * C + c0);
                int sN = sB; float aN = 0.f;
                if (i + 2 < end) { sN = esrc[i + 2]; aN = alpha[(size_t)(i + 2) * HH + h]; }
                acc0 += aA * bf2f(xc.x); acc1 += aA * bf2f(xc.y);
                xc = xn; aA = aB; sB = sN; aB = aN;
            }
        }
    }
    unsigned short* op = outp + (size_t)d * C + c0;
    if (CPL == 4) {
        ushort4 st;
        st.x = f2bf(fmaxf(acc0, 0.f)); st.y = f2bf(fmaxf(acc1, 0.f));
        st.z = f2bf(fmaxf(acc2, 0.f)); st.w = f2bf(fmaxf(acc3, 0.f));
        *(ushort4*)op = st;
    } else {
        ushort2 st;
        st.x = f2bf(fmaxf(acc0, 0.f)); st.y = f2bf(fmaxf(acc1, 0.f));
        *(ushort2*)op = st;
    }
}

__global__ void sem_weights_kernel(const float* __restrict__ partial, const float* __restrict__ q,
                                   float* __restrict__ w, int C, int n)
{
    if (threadIdx.x != 0 || blockIdx.x != 0) return;
    float inv = 1.f / (float)n;
    float s0 = 0.f, s1 = 0.f;
    for (int c = 0; c < C; ++c) {
        s0 += q[c] * partial[c] * inv;
        s1 += q[c] * partial[C + c] * inv;
    }
    float m = fmaxf(s0, s1);
    float e0 = expf(s0 - m), e1 = expf(s1 - m);
    float den = e0 + e1;
    w[0] = e0 / den;
    w[1] = e1 / den;
}

__global__ void combine2_bf16_kernel(const unsigned short* __restrict__ a,
                                     const unsigned short* __restrict__ b,
                                     const float* __restrict__ w, unsigned short* __restrict__ out,
                                     int n8)
{
    int i = blockIdx.x * 256 + threadIdx.x;
    if (i >= n8) return;
    float w0 = w[0], w1 = w[1];
    u16x8 va = ((const u16x8*)a)[i];
    u16x8 vb = ((const u16x8*)b)[i];
    u16x8 o;
    #pragma unroll
    for (int j = 0; j < 8; ++j) o[j] = f2bf(w0 * bf2f(va[j]) + w1 * bf2f(vb[j]));
    ((u16x8*)out)[i] = o;
}

__global__ __launch_bounds__(128) void final_norm_kernel(
    const unsigned short* __restrict__ aggW, const unsigned short* __restrict__ aggC,
    const unsigned short* __restrict__ aggB, const float* __restrict__ w,
    float* __restrict__ out)
{
    __shared__ float red[128];
    int row = blockIdx.x;
    int c = threadIdx.x;
    float v;
    if (row < NN) {
        size_t i = (size_t)row * DOUT + c;
        v = w[0] * bf2f(aggW[i]) + w[1] * bf2f(aggC[i]);
    } else {
        size_t i = (size_t)(row - NN) * DOUT + c;
        v = bf2f(aggB[i]);
    }
    red[c] = v * v;
    __syncthreads();
    for (int s = 64; s > 0; s >>= 1) {
        if (c < s) red[c] += red[c + s];
        __syncthreads();
    }
    float norm = sqrtf(red[0]);
    out[(size_t)row * DOUT + c] = v / fmaxf(norm, 1e-12f);
}

// ------------------------------------------------------------------
extern "C" void kernel_launch(void* const* d_in, const int* in_sizes, int n_in,
                              void* d_out, int out_size, void* d_ws, size_t ws_size,
                              hipStream_t stream)
{
    const float* x_paper   = (const float*)d_in[0];
    const float* x_author  = (const float*)d_in[1];
    const int*   ei_writes = (const int*)d_in[2];
    const int*   ei_wb     = (const int*)d_in[3];
    const int*   ei_cites  = (const int*)d_in[4];
    const float* W0p = (const float*)d_in[5];  const float* b0p = (const float*)d_in[6];
    const float* W0a = (const float*)d_in[7];  const float* b0a = (const float*)d_in[8];
    const float* a0s_w  = (const float*)d_in[9];  const float* a0d_w  = (const float*)d_in[10];
    const float* a0s_wb = (const float*)d_in[11]; const float* a0d_wb = (const float*)d_in[12];
    const float* a0s_c  = (const float*)d_in[13]; const float* a0d_c  = (const float*)d_in[14];
    const float* Wk0 = (const float*)d_in[15]; const float* bk0 = (const float*)d_in[16];
    const float* q0  = (const float*)d_in[17];
    const float* W1p = (const float*)d_in[18]; const float* b1p = (const float*)d_in[19];
    const float* W1a = (const float*)d_in[20]; const float* b1a = (const float*)d_in[21];
    const float* a1s_w  = (const float*)d_in[22]; const float* a1d_w  = (const float*)d_in[23];
    const float* a1s_wb = (const float*)d_in[24]; const float* a1d_wb = (const float*)d_in[25];
    const float* a1s_c  = (const float*)d_in[26]; const float* a1d_c  = (const float*)d_in[27];
    const float* Wk1 = (const float*)d_in[28]; const float* bk1 = (const float*)d_in[29];
    const float* q1  = (const float*)d_in[30];

    float* out = (float*)d_out;

    const size_t NH = (size_t)NN * DHID;
    const size_t NI = (size_t)NN * DIN;
    const size_t NO = (size_t)NN * DOUT;
    const size_t NH2 = NH * 2;
    const size_t NI2 = NI * 2;
    const size_t NO2 = NO * 2;

    char* base = (char*)d_ws;
    unsigned short* xbhP = (unsigned short*)(base + 0);
    unsigned short* xbhA = (unsigned short*)(base + NH2);
    unsigned short* aggW = (unsigned short*)(base + 2 * NH2);
    unsigned short* aggC = (unsigned short*)(base + 3 * NH2);
    unsigned short* aggB = (unsigned short*)(base + 4 * NH2);
    unsigned short* hbP  = (unsigned short*)(base + 0);
    unsigned short* hbA  = aggB;
    unsigned short* x1Pb = (unsigned short*)(base + NH2);
    unsigned short* x1Ab = (unsigned short*)(base + NH2 + NO2);
    unsigned short* agg1W = (unsigned short*)(base + 2 * NH2 + NI2);
    unsigned short* agg1C = (unsigned short*)(base + 2 * NH2 + NI2 + NO2);
    unsigned short* agg1B = (unsigned short*)(base + 2 * NH2 + NI2 + 2 * NO2);

    float* sW_src  = (float*)(base + 204800000);
    float* sW_dst  = sW_src  + NN * H0;
    float* sWB_src = sW_dst  + NN * H0;
    float* sWB_dst = sWB_src + NN * H0;
    float* sC_src  = sWB_dst + NN * H0;
    float* sC_dst  = sC_src  + NN * H0;
    float* alpha3  = (float*)(base + 214400000);
    int* ip     = (int*)(base + 243200000);
    int* offs3  = ip;  ip += 3 * OFFST;
    int* esrc3  = ip;  ip += 3 * NE;
    int* deg3   = ip;  ip += 3 * NN;
    int* bsum3  = ip;  ip += 3 * 256;
    int* boff3  = ip;  ip += 3 * 256;
    unsigned short* wt0p = (unsigned short*)ip;
    unsigned short* wt0a = wt0p + (size_t)DHID * DIN;
    unsigned short* wkt  = wt0a + (size_t)DHID * DIN;
    unsigned short* wt1p = wt0p;
    unsigned short* wt1a = wt1p + (size_t)DOUT * DHID;
    float* tsum = (float*)(wkt + (size_t)DHID * DHID);
    float* wsem = tsum + 512;

    const int NB = (NN + 255) / 256;

    // ---- CSR build (all 3 relations, batched) ----
    hipMemsetAsync(deg3, 0, 3 * NN * sizeof(int), stream);
    hist3_kernel<<<(3 * NE + 255) / 256, 256, 0, stream>>>(ei_writes + NE, ei_wb + NE, ei_cites + NE, deg3);
    block_sum3_kernel<<<dim3(NB, 3), 256, 0, stream>>>(deg3, bsum3);
    scan_bsum3_kernel<<<dim3(1, 3), 256, 0, stream>>>(bsum3, boff3, NB);
    scan_final3_kernel<<<dim3(NB, 3), 256, 0, stream>>>(deg3, boff3, offs3);
    hipMemsetAsync(deg3, 0, 3 * NN * sizeof(int), stream);
    place3_kernel<<<dim3((NE + 255) / 256, 3), 256, 0, stream>>>(ei_writes, ei_wb, ei_cites, offs3, deg3, esrc3);

    // ================= layer 0 =================
    hipMemsetAsync(tsum, 0, 512 * sizeof(float), stream);
    transconv3_kernel<<<dim3((DIN * DHID + 255) / 256, 3), 256, 0, stream>>>(
        W0p, W0a, Wk0, wt0p, wt0a, wkt, DIN, DHID, DHID, DHID);

    dim3 g0(DHID / 128, (NN + 127) / 128, 2);
    gemm_l0_kernel<<<g0, 512, 0, stream>>>(x_paper, x_author, wt0p, wt0a, b0p, b0a, xbhP, xbhA);

    scores_L0_kernel<<<(2 * NN * H0 + 255) / 256, 256, 0, stream>>>(
        xbhP, xbhA, a0d_w, a0s_wb, a0s_c, a0d_c, a0s_w, a0d_wb,
        sW_dst, sWB_src, sC_src, sC_dst, sW_src, sWB_dst);
    dim3 ga0((NN * H0 + 255) / 256, 3);
    seg_alpha3_kernel<<<ga0, 256, 0, stream>>>(
        offs3, esrc3, sW_src, sWB_src, sC_src, sW_dst, sWB_dst, sC_dst, alpha3, H0);
    dim3 gg0(NN / 4, 3);
    gather3_kernel<4, H0, 5><<<gg0, 256, 0, stream>>>(
        offs3, esrc3, alpha3, xbhA, xbhP, xbhP, aggW, aggB, aggC, DHID);

    dim3 gs0(DHID / 128, (NN + 127) / 128, 2);
    sem2_bf16_kernel<<<gs0, 256, 0, stream>>>(aggW, aggC, wkt, bk0, tsum, NN, DHID, DHID);
    sem_weights_kernel<<<1, 64, 0, stream>>>(tsum, q0, wsem, DHID, NN);

    combine2_bf16_kernel<<<(int)((NH / 8 + 255) / 256), 256, 0, stream>>>(aggW, aggC, wsem, hbP, (int)(NH / 8));

    // ================= layer 1 =================
    transconv3_kernel<<<dim3((DHID * DOUT + 255) / 256, 3), 256, 0, stream>>>(
        W1p, W1a, Wk1, wt1p, wt1a, wkt, DHID, DOUT, DOUT, DOUT);

    dim3 g1(DOUT / 128, (NN + 127) / 128, 2);
    gemm_bf16_kernel<<<g1, 256, 0, stream>>>(hbP, hbA, wt1p, wt1a, b1p, b1a, x1Pb, x1Ab, NN, DHID, DOUT);

    hipMemsetAsync(tsum, 0, 2 * DOUT * sizeof(float), stream);

    scores_L1_kernel<<<(2 * NN + 255) / 256, 256, 0, stream>>>(
        x1Pb, x1Ab, a1d_w, a1s_wb, a1s_c, a1d_c, a1s_w, a1d_wb,
        sW_dst, sWB_src, sC_src, sC_dst, sW_src, sWB_dst);
    dim3 ga1((NN + 255) / 256, 3);
    seg_alpha3_kernel<<<ga1, 256, 0, stream>>>(
        offs3, esrc3, sW_src, sWB_src, sC_src, sW_dst, sWB_dst, sC_dst, alpha3, 1);
    dim3 gg1(NN / 4, 3);
    gather3_kernel<2, 1, 7><<<gg1, 256, 0, stream>>>(
        offs3, esrc3, alpha3, x1Ab, x1Pb, x1Pb, agg1W, agg1B, agg1C, DOUT);

    dim3 gs1(DOUT / 128, (NN + 127) / 128, 2);
    sem2_bf16_kernel<<<gs1, 256, 0, stream>>>(agg1W, agg1C, wkt, bk1, tsum, NN, DOUT, DOUT);
    sem_weights_kernel<<<1, 64, 0, stream>>>(tsum, q1, wsem, DOUT, NN);

    final_norm_kernel<<<2 * NN, 128, 0, stream>>>(agg1W, agg1C, agg1B, wsem, out);
}

// Round 16
// 712.809 us; speedup vs baseline: 1.0095x; 1.0095x over previous
//
#include <hip/hip_runtime.h>
#include <math.h>

#define NN 50000
#define NE 300000
#define DIN 768
#define DHID 256
#define DOUT 128
#define H0 8
#define D0 32
#define OFFST (NN + 4)

typedef __attribute__((ext_vector_type(8))) short bf16x8;
typedef __attribute__((ext_vector_type(8))) unsigned short u16x8;
typedef __attribute__((ext_vector_type(4))) float f32x4;

__device__ __forceinline__ unsigned short f2bf(float f) {
    unsigned u = __float_as_uint(f);
    unsigned r = (u + 0x7fffu + ((u >> 16) & 1u)) >> 16;
    return (unsigned short)r;
}
__device__ __forceinline__ float bf2f(unsigned short u) {
    return __uint_as_float(((unsigned)u) << 16);
}

__device__ __forceinline__ void gload16(const void* g, void* l) {
    __builtin_amdgcn_global_load_lds(
        (const __attribute__((address_space(1))) unsigned int*)g,
        (__attribute__((address_space(3))) unsigned int*)l, 16, 0, 0);
}

__device__ __forceinline__ void store_bf8(unsigned short* dst, float4 lo, float4 hi) {
    u16x8 o;
    o[0] = f2bf(lo.x); o[1] = f2bf(lo.y); o[2] = f2bf(lo.z); o[3] = f2bf(lo.w);
    o[4] = f2bf(hi.x); o[5] = f2bf(hi.y); o[6] = f2bf(hi.z); o[7] = f2bf(hi.w);
    *(u16x8*)dst = o;
}

// three transposed-converts in one dispatch (y=0,1: Kab x Nab; y=2: Kc x Ncc)
__global__ void transconv3_kernel(const float* __restrict__ Wa, const float* __restrict__ Wb,
                                  const float* __restrict__ Wc,
                                  unsigned short* __restrict__ Ta, unsigned short* __restrict__ Tb,
                                  unsigned short* __restrict__ Tc,
                                  int Kab, int Nab, int Kc, int Ncc)
{
    int y = blockIdx.y;
    const float* W = (y == 0) ? Wa : ((y == 1) ? Wb : Wc);
    unsigned short* T = (y == 0) ? Ta : ((y == 1) ? Tb : Tc);
    int K = (y == 2) ? Kc : Kab;
    int Nc = (y == 2) ? Ncc : Nab;
    int gid = blockIdx.x * 256 + threadIdx.x;
    if (gid >= K * Nc) return;
    int k = gid / Nc, n = gid - k * Nc;
    T[(size_t)n * K + k] = f2bf(W[gid]);
}

// ---------------- L0 GEMM (round-14 winner, verbatim): fused f32->bf16, reg-A dist-2 + B 3-deep ----
__global__ __launch_bounds__(256) void gemm_l0_kernel(
    const float* __restrict__ A0, const float* __restrict__ A1,
    const unsigned short* __restrict__ Bt0, const unsigned short* __restrict__ Bt1,
    const float* __restrict__ bias0, const float* __restrict__ bias1,
    unsigned short* __restrict__ C0, unsigned short* __restrict__ C1)
{
    constexpr int K  = DIN;     // 768
    constexpr int Nc = DHID;    // 256
    constexpr int NT = K / 32;  // 24
    __shared__ __align__(16) unsigned short As[2][128 * 32];
    __shared__ __align__(16) unsigned short Bs[3][128 * 32];
    const int z = blockIdx.z;
    const float* A = z ? A1 : A0;
    const unsigned short* Bt = z ? Bt1 : Bt0;
    const float* bias = z ? bias1 : bias0;
    unsigned short* C = z ? C1 : C0;
    const int t = threadIdx.x;
    const int lane = t & 63, w = t >> 6;
    const int wr = w >> 1, wc = w & 1;
    const int bm = blockIdx.y * 128, bn = blockIdx.x * 128;

    f32x4 acc[4][4];
    #pragma unroll
    for (int m = 0; m < 4; ++m)
        #pragma unroll
        for (int n = 0; n < 4; ++n)
            acc[m][n] = (f32x4){0.f, 0.f, 0.f, 0.f};

    const int c0 = t, c1 = t + 256;
    const int row0 = c0 >> 2, row1 = c1 >> 2;
    const int g0 = (c0 & 3) ^ ((row0 >> 1) & 3);
    const int g1 = (c1 & 3) ^ ((row1 >> 1) & 3);
    int ar0 = bm + row0; if (ar0 >= NN) ar0 = NN - 1;
    int ar1 = bm + row1; if (ar1 >= NN) ar1 = NN - 1;
    const float* pA0 = A + (size_t)ar0 * K + g0 * 8;
    const float* pA1 = A + (size_t)ar1 * K + g1 * 8;
    const unsigned short* pB0 = Bt + (size_t)(bn + row0) * K + g0 * 8;
    const unsigned short* pB1 = Bt + (size_t)(bn + row1) * K + g1 * 8;

    const int rA = wr * 64 + (lane & 15);
    const int rB = wc * 64 + (lane & 15);
    const int gw = lane >> 4;

    float4 ra[2][4];
    {
        float4 t00 = *(const float4*)(pA0);
        float4 t01 = *(const float4*)(pA0 + 4);
        float4 t10 = *(const float4*)(pA1);
        float4 t11 = *(const float4*)(pA1 + 4);
        gload16(pB0, &Bs[0][c0 * 8]);
        gload16(pB1, &Bs[0][c1 * 8]);
        ra[1][0] = *(const float4*)(pA0 + 32);
        ra[1][1] = *(const float4*)(pA0 + 36);
        ra[1][2] = *(const float4*)(pA1 + 32);
        ra[1][3] = *(const float4*)(pA1 + 36);
        gload16(pB0 + 32, &Bs[1][c0 * 8]);
        gload16(pB1 + 32, &Bs[1][c1 * 8]);
        store_bf8(&As[0][c0 * 8], t00, t01);
        store_bf8(&As[0][c1 * 8], t10, t11);
    }
    asm volatile("s_waitcnt vmcnt(6) lgkmcnt(0)\n\ts_barrier" ::: "memory");

    #pragma unroll
    for (int ti = 0; ti < NT; ++ti) {
        const int rcv = ti & 1;
        const int con = rcv ^ 1;
        if (ti + 2 < NT) {
            const int nk = (ti + 2) * 32;
            ra[rcv][0] = *(const float4*)(pA0 + nk);
            ra[rcv][1] = *(const float4*)(pA0 + nk + 4);
            ra[rcv][2] = *(const float4*)(pA1 + nk);
            ra[rcv][3] = *(const float4*)(pA1 + nk + 4);
            gload16(pB0 + nk, &Bs[(ti + 2) % 3][c0 * 8]);
            gload16(pB1 + nk, &Bs[(ti + 2) % 3][c1 * 8]);
        }
        bf16x8 afr[4], bfr[4];
        #pragma unroll
        for (int m = 0; m < 4; ++m) {
            int r = rA + m * 16;
            afr[m] = *(const bf16x8*)&As[rcv][r * 32 + ((gw ^ ((r >> 1) & 3)) * 8)];
        }
        #pragma unroll
        for (int n = 0; n < 4; ++n) {
            int r = rB + n * 16;
            bfr[n] = *(const bf16x8*)&Bs[ti % 3][r * 32 + ((gw ^ ((r >> 1) & 3)) * 8)];
        }
        #pragma unroll
        for (int m = 0; m < 4; ++m)
            #pragma unroll
            for (int n = 0; n < 4; ++n)
                acc[m][n] = __builtin_amdgcn_mfma_f32_16x16x32_bf16(afr[m], bfr[n], acc[m][n], 0, 0, 0);
        if (ti + 1 < NT) {
            store_bf8(&As[con][c0 * 8], ra[con][0], ra[con][1]);
            store_bf8(&As[con][c1 * 8], ra[con][2], ra[con][3]);
            if (ti + 2 < NT) asm volatile("s_waitcnt vmcnt(6) lgkmcnt(0)\n\ts_barrier" ::: "memory");
            else             asm volatile("s_waitcnt vmcnt(0) lgkmcnt(0)\n\ts_barrier" ::: "memory");
        }
    }

    #pragma unroll
    for (int m = 0; m < 4; ++m) {
        #pragma unroll
        for (int j = 0; j < 4; ++j) {
            int row = bm + wr * 64 + m * 16 + (lane >> 4) * 4 + j;
            if (row >= NN) continue;
            #pragma unroll
            for (int n = 0; n < 4; ++n) {
                int col = bn + wc * 64 + n * 16 + (lane & 15);
                C[(size_t)row * Nc + col] = f2bf(acc[m][n][j] + bias[col]);
            }
        }
    }
}

// ---------------- L1 MFMA GEMM (bf16 A), 3-deep counted-vmcnt pipeline ----------------
__global__ __launch_bounds__(256) void gemm_bf16p_kernel(
    const unsigned short* __restrict__ A0, const unsigned short* __restrict__ A1,
    const unsigned short* __restrict__ Bt0, const unsigned short* __restrict__ Bt1,
    const float* __restrict__ bias0, const float* __restrict__ bias1,
    unsigned short* __restrict__ C0, unsigned short* __restrict__ C1,
    int M, int K, int Nc)
{
    __shared__ __align__(16) unsigned short As[3][128 * 32];
    __shared__ __align__(16) unsigned short Bs[3][128 * 32];
    const int z = blockIdx.z;
    const unsigned short* A  = z ? A1  : A0;
    const unsigned short* Bt = z ? Bt1 : Bt0;
    const float* bias = z ? bias1 : bias0;
    unsigned short* C = z ? C1 : C0;
    const int t = threadIdx.x;
    const int lane = t & 63, w = t >> 6;
    const int wr = w >> 1, wc = w & 1;
    const int bm = blockIdx.y * 128, bn = blockIdx.x * 128;

    f32x4 acc[4][4];
    #pragma unroll
    for (int m = 0; m < 4; ++m)
        #pragma unroll
        for (int n = 0; n < 4; ++n)
            acc[m][n] = (f32x4){0.f, 0.f, 0.f, 0.f};

    const int c0 = t, c1 = t + 256;
    const int row0 = c0 >> 2, row1 = c1 >> 2;
    const int g0 = (c0 & 3) ^ ((row0 >> 1) & 3);
    const int g1 = (c1 & 3) ^ ((row1 >> 1) & 3);
    const int ar0 = (bm + row0 < M) ? (bm + row0) : (M - 1);
    const int ar1 = (bm + row1 < M) ? (bm + row1) : (M - 1);
    const unsigned short* pA0 = A + (size_t)ar0 * K + g0 * 8;
    const unsigned short* pA1 = A + (size_t)ar1 * K + g1 * 8;
    const unsigned short* pB0 = Bt + (size_t)(bn + row0) * K + g0 * 8;
    const unsigned short* pB1 = Bt + (size_t)(bn + row1) * K + g1 * 8;

    const int rA = wr * 64 + (lane & 15);
    const int rB = wc * 64 + (lane & 15);
    const int gw = lane >> 4;
    const int nt = K >> 5;

    // prologue: issue tiles 0 and 1
    gload16(pA0, &As[0][c0 * 8]);
    gload16(pA1, &As[0][c1 * 8]);
    gload16(pB0, &Bs[0][c0 * 8]);
    gload16(pB1, &Bs[0][c1 * 8]);
    gload16(pA0 + 32, &As[1][c0 * 8]);
    gload16(pA1 + 32, &As[1][c1 * 8]);
    gload16(pB0 + 32, &Bs[1][c0 * 8]);
    gload16(pB1 + 32, &Bs[1][c1 * 8]);
    asm volatile("s_waitcnt vmcnt(4) lgkmcnt(0)\n\ts_barrier" ::: "memory");

    for (int ti = 0; ti < nt; ++ti) {
        const int cb = ti % 3;
        if (ti + 2 < nt) {
            const int nk = (ti + 2) << 5;
            const int nb = (ti + 2) % 3;
            gload16(pA0 + nk, &As[nb][c0 * 8]);
            gload16(pA1 + nk, &As[nb][c1 * 8]);
            gload16(pB0 + nk, &Bs[nb][c0 * 8]);
            gload16(pB1 + nk, &Bs[nb][c1 * 8]);
        }
        bf16x8 afr[4], bfr[4];
        #pragma unroll
        for (int m = 0; m < 4; ++m) {
            int r = rA + m * 16;
            afr[m] = *(const bf16x8*)&As[cb][r * 32 + ((gw ^ ((r >> 1) & 3)) * 8)];
        }
        #pragma unroll
        for (int n = 0; n < 4; ++n) {
            int r = rB + n * 16;
            bfr[n] = *(const bf16x8*)&Bs[cb][r * 32 + ((gw ^ ((r >> 1) & 3)) * 8)];
        }
        #pragma unroll
        for (int m = 0; m < 4; ++m)
            #pragma unroll
            for (int n = 0; n < 4; ++n)
                acc[m][n] = __builtin_amdgcn_mfma_f32_16x16x32_bf16(afr[m], bfr[n], acc[m][n], 0, 0, 0);
        if (ti + 1 < nt) {
            if (ti + 2 < nt) asm volatile("s_waitcnt vmcnt(4) lgkmcnt(0)\n\ts_barrier" ::: "memory");
            else             asm volatile("s_waitcnt vmcnt(0) lgkmcnt(0)\n\ts_barrier" ::: "memory");
        }
    }
    #pragma unroll
    for (int m = 0; m < 4; ++m) {
        #pragma unroll
        for (int j = 0; j < 4; ++j) {
            int row = bm + wr * 64 + m * 16 + (lane >> 4) * 4 + j;
            if (row >= M) continue;
            #pragma unroll
            for (int n = 0; n < 4; ++n) {
                int col = bn + wc * 64 + n * 16 + (lane & 15);
                C[(size_t)row * Nc + col] = f2bf(acc[m][n][j] + bias[col]);
            }
        }
    }
}

// ---------------- sem GEMM (batched pair via blockIdx.z), 3-deep counted-vmcnt ----------------
__global__ __launch_bounds__(256) void sem2_bf16_kernel(
    const unsigned short* __restrict__ Aa, const unsigned short* __restrict__ Ab,
    const unsigned short* __restrict__ Bt,
    const float* __restrict__ bk, float* __restrict__ partial0,
    int M, int K, int Nc)
{
    __shared__ __align__(16) unsigned short As[3][128 * 32];
    __shared__ __align__(16) unsigned short Bs[3][128 * 32];
    __shared__ float red[128];
    const int z = blockIdx.z;
    const unsigned short* A = z ? Ab : Aa;
    float* partial = partial0 + z * Nc;
    const int t = threadIdx.x;
    const int lane = t & 63, w = t >> 6;
    const int wr = w >> 1, wc = w & 1;
    const int bm = blockIdx.y * 128, bn = blockIdx.x * 128;

    f32x4 acc[4][4];
    #pragma unroll
    for (int m = 0; m < 4; ++m)
        #pragma unroll
        for (int n = 0; n < 4; ++n)
            acc[m][n] = (f32x4){0.f, 0.f, 0.f, 0.f};

    const int c0 = t, c1 = t + 256;
    const int row0 = c0 >> 2, row1 = c1 >> 2;
    const int g0 = (c0 & 3) ^ ((row0 >> 1) & 3);
    const int g1 = (c1 & 3) ^ ((row1 >> 1) & 3);
    const int ar0 = (bm + row0 < M) ? (bm + row0) : (M - 1);
    const int ar1 = (bm + row1 < M) ? (bm + row1) : (M - 1);
    const unsigned short* pA0 = A + (size_t)ar0 * K + g0 * 8;
    const unsigned short* pA1 = A + (size_t)ar1 * K + g1 * 8;
    const unsigned short* pB0 = Bt + (size_t)(bn + row0) * K + g0 * 8;
    const unsigned short* pB1 = Bt + (size_t)(bn + row1) * K + g1 * 8;

    const int rA = wr * 64 + (lane & 15);
    const int rB = wc * 64 + (lane & 15);
    const int gw = lane >> 4;
    const int nt = K >> 5;

    gload16(pA0, &As[0][c0 * 8]);
    gload16(pA1, &As[0][c1 * 8]);
    gload16(pB0, &Bs[0][c0 * 8]);
    gload16(pB1, &Bs[0][c1 * 8]);
    gload16(pA0 + 32, &As[1][c0 * 8]);
    gload16(pA1 + 32, &As[1][c1 * 8]);
    gload16(pB0 + 32, &Bs[1][c0 * 8]);
    gload16(pB1 + 32, &Bs[1][c1 * 8]);
    asm volatile("s_waitcnt vmcnt(4) lgkmcnt(0)\n\ts_barrier" ::: "memory");

    for (int ti = 0; ti < nt; ++ti) {
        const int cb = ti % 3;
        if (ti + 2 < nt) {
            const int nk = (ti + 2) << 5;
            const int nb = (ti + 2) % 3;
            gload16(pA0 + nk, &As[nb][c0 * 8]);
            gload16(pA1 + nk, &As[nb][c1 * 8]);
            gload16(pB0 + nk, &Bs[nb][c0 * 8]);
            gload16(pB1 + nk, &Bs[nb][c1 * 8]);
        }
        bf16x8 afr[4], bfr[4];
        #pragma unroll
        for (int m = 0; m < 4; ++m) {
            int r = rA + m * 16;
            afr[m] = *(const bf16x8*)&As[cb][r * 32 + ((gw ^ ((r >> 1) & 3)) * 8)];
        }
        #pragma unroll
        for (int n = 0; n < 4; ++n) {
            int r = rB + n * 16;
            bfr[n] = *(const bf16x8*)&Bs[cb][r * 32 + ((gw ^ ((r >> 1) & 3)) * 8)];
        }
        #pragma unroll
        for (int m = 0; m < 4; ++m)
            #pragma unroll
            for (int n = 0; n < 4; ++n)
                acc[m][n] = __builtin_amdgcn_mfma_f32_16x16x32_bf16(afr[m], bfr[n], acc[m][n], 0, 0, 0);
        if (ti + 1 < nt) {
            if (ti + 2 < nt) asm volatile("s_waitcnt vmcnt(4) lgkmcnt(0)\n\ts_barrier" ::: "memory");
            else             asm volatile("s_waitcnt vmcnt(0) lgkmcnt(0)\n\ts_barrier" ::: "memory");
        }
    }
    __syncthreads();
    if (t < 128) red[t] = 0.f;
    __syncthreads();
    #pragma unroll
    for (int n = 0; n < 4; ++n) {
        int lcol = wc * 64 + n * 16 + (lane & 15);
        float b = bk[bn + lcol];
        float s = 0.f;
        #pragma unroll
        for (int m = 0; m < 4; ++m) {
            #pragma unroll
            for (int j = 0; j < 4; ++j) {
                int row = bm + wr * 64 + m * 16 + (lane >> 4) * 4 + j;
                if (row < M) s += tanhf(acc[m][n][j] + b);
            }
        }
        atomicAdd(&red[lcol], s);
    }
    __syncthreads();
    if (t < 128) atomicAdd(&partial[bn + t], red[t]);
}

// ---------------- batched CSR build ----------------
__global__ void hist3_kernel(const int* __restrict__ d0, const int* __restrict__ d1,
                             const int* __restrict__ d2, int* __restrict__ deg3)
{
    int gid = blockIdx.x * 256 + threadIdx.x;
    if (gid >= 3 * NE) return;
    int rel = gid / NE, e = gid - rel * NE;
    const int* dst = (rel == 0) ? d0 : ((rel == 1) ? d1 : d2);
    atomicAdd(&deg3[rel * NN + dst[e]], 1);
}

__global__ void block_sum3_kernel(const int* __restrict__ deg3, int* __restrict__ bsum3)
{
    __shared__ int buf[256];
    int rel = blockIdx.y;
    int i = blockIdx.x * 256 + threadIdx.x;
    buf[threadIdx.x] = (i < NN) ? deg3[rel * NN + i] : 0;
    __syncthreads();
    for (int s = 128; s > 0; s >>= 1) {
        if (threadIdx.x < s) buf[threadIdx.x] += buf[threadIdx.x + s];
        __syncthreads();
    }
    if (threadIdx.x == 0) bsum3[rel * 256 + blockIdx.x] = buf[0];
}

__global__ void scan_bsum3_kernel(const int* __restrict__ bsum3, int* __restrict__ boff3, int nb)
{
    __shared__ int buf[256];
    int rel = blockIdx.y;
    int tid = threadIdx.x;
    int v = (tid < nb) ? bsum3[rel * 256 + tid] : 0;
    buf[tid] = v;
    __syncthreads();
    for (int off = 1; off < 256; off <<= 1) {
        int t = (tid >= off) ? buf[tid - off] : 0;
        __syncthreads();
        buf[tid] += t;
        __syncthreads();
    }
    if (tid < nb) boff3[rel * 256 + tid] = buf[tid] - v;
}

__global__ void scan_final3_kernel(const int* __restrict__ deg3, const int* __restrict__ boff3,
                                   int* __restrict__ offs3)
{
    __shared__ int buf[256];
    int rel = blockIdx.y;
    int tid = threadIdx.x, b = blockIdx.x;
    int i = b * 256 + tid;
    int v = (i < NN) ? deg3[rel * NN + i] : 0;
    buf[tid] = v;
    __syncthreads();
    for (int off = 1; off < 256; off <<= 1) {
        int t = (tid >= off) ? buf[tid - off] : 0;
        __syncthreads();
        buf[tid] += t;
        __syncthreads();
    }
    int* offs = offs3 + rel * OFFST;
    if (i < NN) offs[i] = boff3[rel * 256 + b] + buf[tid] - v;
    if (i == NN - 1) offs[NN] = boff3[rel * 256 + b] + buf[tid];
}

__global__ void place3_kernel(const int* __restrict__ s0, const int* __restrict__ s1,
                              const int* __restrict__ s2,
                              const int* __restrict__ offs3, int* __restrict__ cnt3,
                              int* __restrict__ esrc3)
{
    int rel = blockIdx.y;
    int e = blockIdx.x * 256 + threadIdx.x;
    if (e >= NE) return;
    const int* srcdst = (rel == 0) ? s0 : ((rel == 1) ? s1 : s2);
    int src = srcdst[e];
    int d = srcdst[NE + e];
    int p = offs3[rel * OFFST + d] + atomicAdd(&cnt3[rel * NN + d], 1);
    esrc3[rel * NE + p] = src;
}

// ---------------- fused per-layer node scores ----------------
__global__ void scores_L0_kernel(
    const unsigned short* __restrict__ xp, const unsigned short* __restrict__ xa,
    const float* __restrict__ a_dw, const float* __restrict__ a_swb,
    const float* __restrict__ a_sc, const float* __restrict__ a_dc,
    const float* __restrict__ a_sw, const float* __restrict__ a_dwb,
    float* __restrict__ sW_dst, float* __restrict__ sWB_src,
    float* __restrict__ sC_src, float* __restrict__ sC_dst,
    float* __restrict__ sW_src, float* __restrict__ sWB_dst)
{
    int gid = blockIdx.x * 256 + threadIdx.x;
    int half = NN * H0;
    if (gid >= 2 * half) return;
    if (gid < half) {
        int node = gid >> 3, h = gid & 7;
        const unsigned short* xr = xp + (size_t)node * DHID + h * D0;
        float xv[D0];
        #pragma unroll
        for (int j = 0; j < 4; ++j) {
            u16x8 v = ((const u16x8*)xr)[j];
            #pragma unroll
            for (int k = 0; k < 8; ++k) xv[j * 8 + k] = bf2f(v[k]);
        }
        const float* p0 = a_dw  + h * D0;
        const float* p1 = a_swb + h * D0;
        const float* p2 = a_sc  + h * D0;
        const float* p3 = a_dc  + h * D0;
        float d0 = 0.f, d1 = 0.f, d2 = 0.f, d3 = 0.f;
        #pragma unroll
        for (int k = 0; k < D0; ++k) {
            float x = xv[k];
            d0 += x * p0[k]; d1 += x * p1[k]; d2 += x * p2[k]; d3 += x * p3[k];
        }
        sW_dst[gid] = d0; sWB_src[gid] = d1; sC_src[gid] = d2; sC_dst[gid] = d3;
    } else {
        int g = gid - half;
        int node = g >> 3, h = g & 7;
        const unsigned short* xr = xa + (size_t)node * DHID + h * D0;
        float xv[D0];
        #pragma unroll
        for (int j = 0; j < 4; ++j) {
            u16x8 v = ((const u16x8*)xr)[j];
            #pragma unroll
            for (int k = 0; k < 8; ++k) xv[j * 8 + k] = bf2f(v[k]);
        }
        const float* p0 = a_sw  + h * D0;
        const float* p1 = a_dwb + h * D0;
        float d0 = 0.f, d1 = 0.f;
        #pragma unroll
        for (int k = 0; k < D0; ++k) {
            float x = xv[k];
            d0 += x * p0[k]; d1 += x * p1[k];
        }
        sW_src[g] = d0; sWB_dst[g] = d1;
    }
}

__global__ void scores_L1_kernel(
    const unsigned short* __restrict__ xp, const unsigned short* __restrict__ xa,
    const float* __restrict__ a_dw, const float* __restrict__ a_swb,
    const float* __restrict__ a_sc, const float* __restrict__ a_dc,
    const float* __restrict__ a_sw, const float* __restrict__ a_dwb,
    float* __restrict__ sW_dst, float* __restrict__ sWB_src,
    float* __restrict__ sC_src, float* __restrict__ sC_dst,
    float* __restrict__ sW_src, float* __restrict__ sWB_dst)
{
    int gid = blockIdx.x * 256 + threadIdx.x;
    if (gid >= 2 * NN) return;
    if (gid < NN) {
        const unsigned short* xr = xp + (size_t)gid * DOUT;
        float d0 = 0.f, d1 = 0.f, d2 = 0.f, d3 = 0.f;
        for (int j = 0; j < DOUT / 8; ++j) {
            u16x8 v = ((const u16x8*)xr)[j];
            #pragma unroll
            for (int k = 0; k < 8; ++k) {
                float x = bf2f(v[k]);
                int c = j * 8 + k;
                d0 += x * a_dw[c]; d1 += x * a_swb[c]; d2 += x * a_sc[c]; d3 += x * a_dc[c];
            }
        }
        sW_dst[gid] = d0; sWB_src[gid] = d1; sC_src[gid] = d2; sC_dst[gid] = d3;
    } else {
        int g = gid - NN;
        const unsigned short* xr = xa + (size_t)g * DOUT;
        float d0 = 0.f, d1 = 0.f;
        for (int j = 0; j < DOUT / 8; ++j) {
            u16x8 v = ((const u16x8*)xr)[j];
            #pragma unroll
            for (int k = 0; k < 8; ++k) {
                float x = bf2f(v[k]);
                int c = j * 8 + k;
                d0 += x * a_sw[c]; d1 += x * a_dwb[c];
            }
        }
        sW_src[g] = d0; sWB_dst[g] = d1;
    }
}

// ---------------- batched per-(dst,head) segment softmax -> alpha ----------------
__global__ void seg_alpha3_kernel(
    const int* __restrict__ offs3, const int* __restrict__ esrc3,
    const float* __restrict__ ss0, const float* __restrict__ ss1, const float* __restrict__ ss2,
    const float* __restrict__ sd0, const float* __restrict__ sd1, const float* __restrict__ sd2,
    float* __restrict__ alpha3, int H)
{
    int rel = blockIdx.y;
    const int* offs = offs3 + rel * OFFST;
    const int* esrc = esrc3 + rel * NE;
    const float* ssrc = (rel == 0) ? ss0 : ((rel == 1) ? ss1 : ss2);
    const float* sdst = (rel == 0) ? sd0 : ((rel == 1) ? sd1 : sd2);
    float* alpha = alpha3 + (size_t)rel * NE * H0;
    int gid = blockIdx.x * 256 + threadIdx.x;
    if (gid >= NN * H) return;
    int d = gid / H, h = gid - d * H;
    int beg = offs[d], end = offs[d + 1];
    float sd = sdst[gid];
    float m = -INFINITY, den = 0.f;
    for (int i = beg; i < end; ++i) {
        int s = esrc[i];
        float v = ssrc[s * H + h] + sd;
        v = (v >= 0.f) ? v : 0.2f * v;
        if (v > m) { den = den * expf(m - v) + 1.f; m = v; }
        else       den += expf(v - m);
    }
    float inv = 1.f / (den + 1e-16f);
    for (int i = beg; i < end; ++i) {
        int s = esrc[i];
        float v = ssrc[s * H + h] + sd;
        v = (v >= 0.f) ? v : 0.2f * v;
        alpha[(size_t)i * H + h] = expf(v - m) * inv;
    }
}

// ---------------- batched weighted gather, 2-deep software pipeline ----------------
template<int CPL, int HH, int DSH>
__global__ __launch_bounds__(256) void gather3_kernel(
    const int* __restrict__ offs3, const int* __restrict__ esrc3,
    const float* __restrict__ alpha3,
    const unsigned short* __restrict__ x0, const unsigned short* __restrict__ x1,
    const unsigned short* __restrict__ x2,
    unsigned short* __restrict__ o0, unsigned short* __restrict__ o1,
    unsigned short* __restrict__ o2, int C)
{
    int rel = blockIdx.y;
    const int* offs = offs3 + rel * OFFST;
    const int* esrc = esrc3 + rel * NE;
    const float* alpha = alpha3 + (size_t)rel * NE * H0;
    const unsigned short* x = (rel == 0) ? x0 : ((rel == 1) ? x1 : x2);
    unsigned short* outp = (rel == 0) ? o0 : ((rel == 1) ? o1 : o2);

    int wid = threadIdx.x >> 6, lane = threadIdx.x & 63;
    int d = blockIdx.x * 4 + wid;
    int c0 = lane * CPL;
    int h = c0 >> DSH;
    int beg = offs[d], end = offs[d + 1];
    float acc0 = 0.f, acc1 = 0.f, acc2 = 0.f, acc3 = 0.f;
    int n = end - beg;
    if (n > 0) {
        int sA = esrc[beg];
        float aA = alpha[(size_t)beg * HH + h];
        int sB = sA; float aB = 0.f;
        if (n > 1) { sB = esrc[beg + 1]; aB = alpha[(size_t)(beg + 1) * HH + h]; }
        if (CPL == 4) {
            ushort4 xc = *(const ushort4*)(x + (size_t)sA * C + c0);
            for (int i = beg; i < end; ++i) {
                ushort4 xn = xc;
                if (i + 1 < end) xn = *(const ushort4*)(x + (size_t)sB * C + c0);
                int sN = sB; float aN = 0.f;
                if (i + 2 < end) { sN = esrc[i + 2]; aN = alpha[(size_t)(i + 2) * HH + h]; }
                acc0 += aA * bf2f(xc.x); acc1 += aA * bf2f(xc.y);
                acc2 += aA * bf2f(xc.z); acc3 += aA * bf2f(xc.w);
                xc = xn; aA = aB; sB = sN; aB = aN;
            }
        } else {
            ushort2 xc = *(const ushort2*)(x + (size_t)sA * C + c0);
            for (int i = beg; i < end; ++i) {
                ushort2 xn = xc;
                if (i + 1 < end) xn = *(const ushort2*)(x + (size_t)sB * C + c0);
                int sN = sB; float aN = 0.f;
                if (i + 2 < end) { sN = esrc[i + 2]; aN = alpha[(size_t)(i + 2) * HH + h]; }
                acc0 += aA * bf2f(xc.x); acc1 += aA * bf2f(xc.y);
                xc = xn; aA = aB; sB = sN; aB = aN;
            }
        }
    }
    unsigned short* op = outp + (size_t)d * C + c0;
    if (CPL == 4) {
        ushort4 st;
        st.x = f2bf(fmaxf(acc0, 0.f)); st.y = f2bf(fmaxf(acc1, 0.f));
        st.z = f2bf(fmaxf(acc2, 0.f)); st.w = f2bf(fmaxf(acc3, 0.f));
        *(ushort4*)op = st;
    } else {
        ushort2 st;
        st.x = f2bf(fmaxf(acc0, 0.f)); st.y = f2bf(fmaxf(acc1, 0.f));
        *(ushort2*)op = st;
    }
}

__global__ void sem_weights_kernel(const float* __restrict__ partial, const float* __restrict__ q,
                                   float* __restrict__ w, int C, int n)
{
    if (threadIdx.x != 0 || blockIdx.x != 0) return;
    float inv = 1.f / (float)n;
    float s0 = 0.f, s1 = 0.f;
    for (int c = 0; c < C; ++c) {
        s0 += q[c] * partial[c] * inv;
        s1 += q[c] * partial[C + c] * inv;
    }
    float m = fmaxf(s0, s1);
    float e0 = expf(s0 - m), e1 = expf(s1 - m);
    float den = e0 + e1;
    w[0] = e0 / den;
    w[1] = e1 / den;
}

__global__ void combine2_bf16_kernel(const unsigned short* __restrict__ a,
                                     const unsigned short* __restrict__ b,
                                     const float* __restrict__ w, unsigned short* __restrict__ out,
                                     int n8)
{
    int i = blockIdx.x * 256 + threadIdx.x;
    if (i >= n8) return;
    float w0 = w[0], w1 = w[1];
    u16x8 va = ((const u16x8*)a)[i];
    u16x8 vb = ((const u16x8*)b)[i];
    u16x8 o;
    #pragma unroll
    for (int j = 0; j < 8; ++j) o[j] = f2bf(w0 * bf2f(va[j]) + w1 * bf2f(vb[j]));
    ((u16x8*)out)[i] = o;
}

__global__ __launch_bounds__(128) void final_norm_kernel(
    const unsigned short* __restrict__ aggW, const unsigned short* __restrict__ aggC,
    const unsigned short* __restrict__ aggB, const float* __restrict__ w,
    float* __restrict__ out)
{
    __shared__ float red[128];
    int row = blockIdx.x;
    int c = threadIdx.x;
    float v;
    if (row < NN) {
        size_t i = (size_t)row * DOUT + c;
        v = w[0] * bf2f(aggW[i]) + w[1] * bf2f(aggC[i]);
    } else {
        size_t i = (size_t)(row - NN) * DOUT + c;
        v = bf2f(aggB[i]);
    }
    red[c] = v * v;
    __syncthreads();
    for (int s = 64; s > 0; s >>= 1) {
        if (c < s) red[c] += red[c + s];
        __syncthreads();
    }
    float norm = sqrtf(red[0]);
    out[(size_t)row * DOUT + c] = v / fmaxf(norm, 1e-12f);
}

// ------------------------------------------------------------------
extern "C" void kernel_launch(void* const* d_in, const int* in_sizes, int n_in,
                              void* d_out, int out_size, void* d_ws, size_t ws_size,
                              hipStream_t stream)
{
    const float* x_paper   = (const float*)d_in[0];
    const float* x_author  = (const float*)d_in[1];
    const int*   ei_writes = (const int*)d_in[2];
    const int*   ei_wb     = (const int*)d_in[3];
    const int*   ei_cites  = (const int*)d_in[4];
    const float* W0p = (const float*)d_in[5];  const float* b0p = (const float*)d_in[6];
    const float* W0a = (const float*)d_in[7];  const float* b0a = (const float*)d_in[8];
    const float* a0s_w  = (const float*)d_in[9];  const float* a0d_w  = (const float*)d_in[10];
    const float* a0s_wb = (const float*)d_in[11]; const float* a0d_wb = (const float*)d_in[12];
    const float* a0s_c  = (const float*)d_in[13]; const float* a0d_c  = (const float*)d_in[14];
    const float* Wk0 = (const float*)d_in[15]; const float* bk0 = (const float*)d_in[16];
    const float* q0  = (const float*)d_in[17];
    const float* W1p = (const float*)d_in[18]; const float* b1p = (const float*)d_in[19];
    const float* W1a = (const float*)d_in[20]; const float* b1a = (const float*)d_in[21];
    const float* a1s_w  = (const float*)d_in[22]; const float* a1d_w  = (const float*)d_in[23];
    const float* a1s_wb = (const float*)d_in[24]; const float* a1d_wb = (const float*)d_in[25];
    const float* a1s_c  = (const float*)d_in[26]; const float* a1d_c  = (const float*)d_in[27];
    const float* Wk1 = (const float*)d_in[28]; const float* bk1 = (const float*)d_in[29];
    const float* q1  = (const float*)d_in[30];

    float* out = (float*)d_out;

    const size_t NH = (size_t)NN * DHID;
    const size_t NI = (size_t)NN * DIN;
    const size_t NO = (size_t)NN * DOUT;
    const size_t NH2 = NH * 2;
    const size_t NI2 = NI * 2;
    const size_t NO2 = NO * 2;

    char* base = (char*)d_ws;
    unsigned short* xbhP = (unsigned short*)(base + 0);
    unsigned short* xbhA = (unsigned short*)(base + NH2);
    unsigned short* aggW = (unsigned short*)(base + 2 * NH2);
    unsigned short* aggC = (unsigned short*)(base + 3 * NH2);
    unsigned short* aggB = (unsigned short*)(base + 4 * NH2);
    unsigned short* hbP  = (unsigned short*)(base + 0);
    unsigned short* hbA  = aggB;
    unsigned short* x1Pb = (unsigned short*)(base + NH2);
    unsigned short* x1Ab = (unsigned short*)(base + NH2 + NO2);
    unsigned short* agg1W = (unsigned short*)(base + 2 * NH2 + NI2);
    unsigned short* agg1C = (unsigned short*)(base + 2 * NH2 + NI2 + NO2);
    unsigned short* agg1B = (unsigned short*)(base + 2 * NH2 + NI2 + 2 * NO2);

    float* sW_src  = (float*)(base + 204800000);
    float* sW_dst  = sW_src  + NN * H0;
    float* sWB_src = sW_dst  + NN * H0;
    float* sWB_dst = sWB_src + NN * H0;
    float* sC_src  = sWB_dst + NN * H0;
    float* sC_dst  = sC_src  + NN * H0;
    float* alpha3  = (float*)(base + 214400000);
    int* ip     = (int*)(base + 243200000);
    int* offs3  = ip;  ip += 3 * OFFST;
    int* esrc3  = ip;  ip += 3 * NE;
    int* deg3   = ip;  ip += 3 * NN;
    int* bsum3  = ip;  ip += 3 * 256;
    int* boff3  = ip;  ip += 3 * 256;
    unsigned short* wt0p = (unsigned short*)ip;
    unsigned short* wt0a = wt0p + (size_t)DHID * DIN;
    unsigned short* wkt  = wt0a + (size_t)DHID * DIN;
    unsigned short* wt1p = wt0p;
    unsigned short* wt1a = wt1p + (size_t)DOUT * DHID;
    float* tsum = (float*)(wkt + (size_t)DHID * DHID);
    float* wsem = tsum + 512;

    const int NB = (NN + 255) / 256;

    // ---- CSR build (all 3 relations, batched) ----
    hipMemsetAsync(deg3, 0, 3 * NN * sizeof(int), stream);
    hist3_kernel<<<(3 * NE + 255) / 256, 256, 0, stream>>>(ei_writes + NE, ei_wb + NE, ei_cites + NE, deg3);
    block_sum3_kernel<<<dim3(NB, 3), 256, 0, stream>>>(deg3, bsum3);
    scan_bsum3_kernel<<<dim3(1, 3), 256, 0, stream>>>(bsum3, boff3, NB);
    scan_final3_kernel<<<dim3(NB, 3), 256, 0, stream>>>(deg3, boff3, offs3);
    hipMemsetAsync(deg3, 0, 3 * NN * sizeof(int), stream);
    place3_kernel<<<dim3((NE + 255) / 256, 3), 256, 0, stream>>>(ei_writes, ei_wb, ei_cites, offs3, deg3, esrc3);

    // ================= layer 0 =================
    hipMemsetAsync(tsum, 0, 512 * sizeof(float), stream);
    transconv3_kernel<<<dim3((DIN * DHID + 255) / 256, 3), 256, 0, stream>>>(
        W0p, W0a, Wk0, wt0p, wt0a, wkt, DIN, DHID, DHID, DHID);

    dim3 g0(DHID / 128, (NN + 127) / 128, 2);
    gemm_l0_kernel<<<g0, 256, 0, stream>>>(x_paper, x_author, wt0p, wt0a, b0p, b0a, xbhP, xbhA);

    scores_L0_kernel<<<(2 * NN * H0 + 255) / 256, 256, 0, stream>>>(
        xbhP, xbhA, a0d_w, a0s_wb, a0s_c, a0d_c, a0s_w, a0d_wb,
        sW_dst, sWB_src, sC_src, sC_dst, sW_src, sWB_dst);
    dim3 ga0((NN * H0 + 255) / 256, 3);
    seg_alpha3_kernel<<<ga0, 256, 0, stream>>>(
        offs3, esrc3, sW_src, sWB_src, sC_src, sW_dst, sWB_dst, sC_dst, alpha3, H0);
    dim3 gg0(NN / 4, 3);
    gather3_kernel<4, H0, 5><<<gg0, 256, 0, stream>>>(
        offs3, esrc3, alpha3, xbhA, xbhP, xbhP, aggW, aggB, aggC, DHID);

    dim3 gs0(DHID / 128, (NN + 127) / 128, 2);
    sem2_bf16_kernel<<<gs0, 256, 0, stream>>>(aggW, aggC, wkt, bk0, tsum, NN, DHID, DHID);
    sem_weights_kernel<<<1, 64, 0, stream>>>(tsum, q0, wsem, DHID, NN);

    combine2_bf16_kernel<<<(int)((NH / 8 + 255) / 256), 256, 0, stream>>>(aggW, aggC, wsem, hbP, (int)(NH / 8));

    // ================= layer 1 =================
    transconv3_kernel<<<dim3((DHID * DOUT + 255) / 256, 3), 256, 0, stream>>>(
        W1p, W1a, Wk1, wt1p, wt1a, wkt, DHID, DOUT, DOUT, DOUT);

    dim3 g1(DOUT / 128, (NN + 127) / 128, 2);
    gemm_bf16p_kernel<<<g1, 256, 0, stream>>>(hbP, hbA, wt1p, wt1a, b1p, b1a, x1Pb, x1Ab, NN, DHID, DOUT);

    hipMemsetAsync(tsum, 0, 2 * DOUT * sizeof(float), stream);

    scores_L1_kernel<<<(2 * NN + 255) / 256, 256, 0, stream>>>(
        x1Pb, x1Ab, a1d_w, a1s_wb, a1s_c, a1d_c, a1s_w, a1d_wb,
        sW_dst, sWB_src, sC_src, sC_dst, sW_src, sWB_dst);
    dim3 ga1((NN + 255) / 256, 3);
    seg_alpha3_kernel<<<ga1, 256, 0, stream>>>(
        offs3, esrc3, sW_src, sWB_src, sC_src, sW_dst, sWB_dst, sC_dst, alpha3, 1);
    dim3 gg1(NN / 4, 3);
    gather3_kernel<2, 1, 7><<<gg1, 256, 0, stream>>>(
        offs3, esrc3, alpha3, x1Ab, x1Pb, x1Pb, agg1W, agg1B, agg1C, DOUT);

    dim3 gs1(DOUT / 128, (NN + 127) / 128, 2);
    sem2_bf16_kernel<<<gs1, 256, 0, stream>>>(agg1W, agg1C, wkt, bk1, tsum, NN, DOUT, DOUT);
    sem_weights_kernel<<<1, 64, 0, stream>>>(tsum, q1, wsem, DOUT, NN);

    final_norm_kernel<<<2 * NN, 128, 0, stream>>>(agg1W, agg1C, agg1B, wsem, out);
}